// Round 1
// baseline (231.641 us; speedup 1.0000x reference)
//
#include <hip/hip_runtime.h>

// IDWT 1D db4 as a transposed convolution.
// Shapes: L,H = (8,64,4096) fp32 ; out = (8,64,8192) fp32.
// out[row, j] = sum_k band_low[k]*L[row, (j+3-k)/2] + band_high[k]*H[row, (j+3-k)/2]
// over k with (j+3-k) even and r in [0,4096).

#define LIN   4096
#define LOUT  8192
#define NROWS 512          // 8*64
#define UPER  2048         // LOUT/4 float4 outputs per row

// band_low  = DEC_LO reversed ; band_high = DEC_HI reversed
#define BL0  0.23037781330885523f
#define BL1  0.7148465705525415f
#define BL2  0.6308807679295904f
#define BL3 -0.02798376941698385f
#define BL4 -0.18703481171888114f
#define BL5  0.030841381835986965f
#define BL6  0.032883011666982945f
#define BL7 -0.010597401784997278f

#define BH0 -0.010597401784997278f
#define BH1  0.032883011666982945f
#define BH2  0.030841381835986965f
#define BH3  0.18703481171888114f
#define BH4 -0.02798376941698385f
#define BH5 -0.6308807679295904f
#define BH6  0.7148465705525415f
#define BH7 -0.23037781330885523f

__global__ __launch_bounds__(256) void idwt_db4_kernel(
    const float* __restrict__ L, const float* __restrict__ H,
    float* __restrict__ out)
{
    const int idx = blockIdx.x * 256 + threadIdx.x;   // 512*2048 threads total
    const int row = idx >> 11;                        // / UPER
    const int u   = idx & (UPER - 1);

    const float* __restrict__ Lr = L + (size_t)row * LIN;
    const float* __restrict__ Hr = H + (size_t)row * LIN;

    // Need inputs r = 2u-2 .. 2u+3  (l[i] = L[2u-2+i])
    float l0, l1, l2, l3, l4, l5;
    float h0, h1, h2, h3, h4, h5;

    if (u >= 1 && u <= UPER - 2) {
        const int r0 = 2 * u - 2;                     // even -> 8B aligned
        const float2* L2 = (const float2*)(Lr + r0);
        const float2* H2 = (const float2*)(Hr + r0);
        float2 a0 = L2[0], a1 = L2[1], a2 = L2[2];
        float2 b0 = H2[0], b1 = H2[1], b2 = H2[2];
        l0 = a0.x; l1 = a0.y; l2 = a1.x; l3 = a1.y; l4 = a2.x; l5 = a2.y;
        h0 = b0.x; h1 = b0.y; h2 = b1.x; h3 = b1.y; h4 = b2.x; h5 = b2.y;
    } else {
        const int r0 = 2 * u - 2;
        l0 = (r0 + 0 >= 0 && r0 + 0 < LIN) ? Lr[r0 + 0] : 0.0f;
        l1 = (r0 + 1 >= 0 && r0 + 1 < LIN) ? Lr[r0 + 1] : 0.0f;
        l2 = (r0 + 2 >= 0 && r0 + 2 < LIN) ? Lr[r0 + 2] : 0.0f;
        l3 = (r0 + 3 >= 0 && r0 + 3 < LIN) ? Lr[r0 + 3] : 0.0f;
        l4 = (r0 + 4 >= 0 && r0 + 4 < LIN) ? Lr[r0 + 4] : 0.0f;
        l5 = (r0 + 5 >= 0 && r0 + 5 < LIN) ? Lr[r0 + 5] : 0.0f;
        h0 = (r0 + 0 >= 0 && r0 + 0 < LIN) ? Hr[r0 + 0] : 0.0f;
        h1 = (r0 + 1 >= 0 && r0 + 1 < LIN) ? Hr[r0 + 1] : 0.0f;
        h2 = (r0 + 2 >= 0 && r0 + 2 < LIN) ? Hr[r0 + 2] : 0.0f;
        h3 = (r0 + 3 >= 0 && r0 + 3 < LIN) ? Hr[r0 + 3] : 0.0f;
        h4 = (r0 + 4 >= 0 && r0 + 4 < LIN) ? Hr[r0 + 4] : 0.0f;
        h5 = (r0 + 5 >= 0 && r0 + 5 < LIN) ? Hr[r0 + 5] : 0.0f;
    }

    // j = 4u   (even, r = 2u+1,2u,2u-1,2u-2 with taps bl1,bl3,bl5,bl7)
    float o0 = BL1 * l3 + BL3 * l2 + BL5 * l1 + BL7 * l0
             + BH1 * h3 + BH3 * h2 + BH5 * h1 + BH7 * h0;
    // j = 4u+1 (odd,  r = 2u+2,2u+1,2u,2u-1 with taps bl0,bl2,bl4,bl6)
    float o1 = BL0 * l4 + BL2 * l3 + BL4 * l2 + BL6 * l1
             + BH0 * h4 + BH2 * h3 + BH4 * h2 + BH6 * h1;
    // j = 4u+2 (even, r = 2u+2,2u+1,2u,2u-1 with taps bl1,bl3,bl5,bl7)
    float o2 = BL1 * l4 + BL3 * l3 + BL5 * l2 + BL7 * l1
             + BH1 * h4 + BH3 * h3 + BH5 * h2 + BH7 * h1;
    // j = 4u+3 (odd,  r = 2u+3,2u+2,2u+1,2u with taps bl0,bl2,bl4,bl6)
    float o3 = BL0 * l5 + BL2 * l4 + BL4 * l3 + BL6 * l2
             + BH0 * h5 + BH2 * h4 + BH4 * h3 + BH6 * h2;

    float4* outv = (float4*)(out + (size_t)row * LOUT);
    outv[u] = make_float4(o0, o1, o2, o3);
}

extern "C" void kernel_launch(void* const* d_in, const int* in_sizes, int n_in,
                              void* d_out, int out_size, void* d_ws, size_t ws_size,
                              hipStream_t stream)
{
    const float* L = (const float*)d_in[0];
    const float* H = (const float*)d_in[1];
    float* out = (float*)d_out;

    const int total_threads = NROWS * UPER;           // 1,048,576
    const int blocks = total_threads / 256;           // 4096
    idwt_db4_kernel<<<blocks, 256, 0, stream>>>(L, H, out);
}

// Round 3
// 226.742 us; speedup vs baseline: 1.0216x; 1.0216x over previous
//
#include <hip/hip_runtime.h>

// IDWT 1D db4 as a transposed convolution.
// Shapes: L,H = (8,64,4096) fp32 ; out = (8,64,8192) fp32.
// Each thread computes 8 consecutive outputs j = 8t .. 8t+7, needing the
// 8-element windows L[4t-2 .. 4t+5] and H[4t-2 .. 4t+5].

#define LIN   4096
#define LOUT  8192
#define NROWS 512          // 8*64
#define TPER  1024         // LOUT/8 threads per row

typedef float vfloat4 __attribute__((ext_vector_type(4)));

// band_low  = DEC_LO reversed ; band_high = DEC_HI reversed
#define BL0  0.23037781330885523f
#define BL1  0.7148465705525415f
#define BL2  0.6308807679295904f
#define BL3 -0.02798376941698385f
#define BL4 -0.18703481171888114f
#define BL5  0.030841381835986965f
#define BL6  0.032883011666982945f
#define BL7 -0.010597401784997278f

#define BH0 -0.010597401784997278f
#define BH1  0.032883011666982945f
#define BH2  0.030841381835986965f
#define BH3  0.18703481171888114f
#define BH4 -0.02798376941698385f
#define BH5 -0.6308807679295904f
#define BH6  0.7148465705525415f
#define BH7 -0.23037781330885523f

__global__ __launch_bounds__(256) void idwt_db4_kernel(
    const float* __restrict__ L, const float* __restrict__ H,
    float* __restrict__ out)
{
    const int idx = blockIdx.x * 256 + threadIdx.x;   // 512*1024 threads total
    const int row = idx >> 10;                        // / TPER
    const int t   = idx & (TPER - 1);

    const float* __restrict__ Lr = L + (size_t)row * LIN;
    const float* __restrict__ Hr = H + (size_t)row * LIN;

    // w[i] = L[4t-2+i], v[i] = H[4t-2+i], i = 0..7
    float w0, w1, w2, w3, w4, w5, w6, w7;
    float v0, v1, v2, v3, v4, v5, v6, v7;

    const int r0 = 4 * t - 2;
    if (t >= 1 && t <= TPER - 2) {
        const float2* L2 = (const float2*)(Lr + r0);  // r0 even -> 8B aligned
        const float2* H2 = (const float2*)(Hr + r0);
        float2 a0 = L2[0], a1 = L2[1], a2 = L2[2], a3 = L2[3];
        float2 b0 = H2[0], b1 = H2[1], b2 = H2[2], b3 = H2[3];
        w0 = a0.x; w1 = a0.y; w2 = a1.x; w3 = a1.y;
        w4 = a2.x; w5 = a2.y; w6 = a3.x; w7 = a3.y;
        v0 = b0.x; v1 = b0.y; v2 = b1.x; v3 = b1.y;
        v4 = b2.x; v5 = b2.y; v6 = b3.x; v7 = b3.y;
    } else {
        w0 = (r0 + 0 >= 0 && r0 + 0 < LIN) ? Lr[r0 + 0] : 0.0f;
        w1 = (r0 + 1 >= 0 && r0 + 1 < LIN) ? Lr[r0 + 1] : 0.0f;
        w2 = (r0 + 2 >= 0 && r0 + 2 < LIN) ? Lr[r0 + 2] : 0.0f;
        w3 = (r0 + 3 >= 0 && r0 + 3 < LIN) ? Lr[r0 + 3] : 0.0f;
        w4 = (r0 + 4 >= 0 && r0 + 4 < LIN) ? Lr[r0 + 4] : 0.0f;
        w5 = (r0 + 5 >= 0 && r0 + 5 < LIN) ? Lr[r0 + 5] : 0.0f;
        w6 = (r0 + 6 >= 0 && r0 + 6 < LIN) ? Lr[r0 + 6] : 0.0f;
        w7 = (r0 + 7 >= 0 && r0 + 7 < LIN) ? Lr[r0 + 7] : 0.0f;
        v0 = (r0 + 0 >= 0 && r0 + 0 < LIN) ? Hr[r0 + 0] : 0.0f;
        v1 = (r0 + 1 >= 0 && r0 + 1 < LIN) ? Hr[r0 + 1] : 0.0f;
        v2 = (r0 + 2 >= 0 && r0 + 2 < LIN) ? Hr[r0 + 2] : 0.0f;
        v3 = (r0 + 3 >= 0 && r0 + 3 < LIN) ? Hr[r0 + 3] : 0.0f;
        v4 = (r0 + 4 >= 0 && r0 + 4 < LIN) ? Hr[r0 + 4] : 0.0f;
        v5 = (r0 + 5 >= 0 && r0 + 5 < LIN) ? Hr[r0 + 5] : 0.0f;
        v6 = (r0 + 6 >= 0 && r0 + 6 < LIN) ? Hr[r0 + 6] : 0.0f;
        v7 = (r0 + 7 >= 0 && r0 + 7 < LIN) ? Hr[r0 + 7] : 0.0f;
    }

    // Group A: outputs j = 8t .. 8t+3 (window w0..w5 / v0..v5)
    float o0 = BL1 * w3 + BL3 * w2 + BL5 * w1 + BL7 * w0
             + BH1 * v3 + BH3 * v2 + BH5 * v1 + BH7 * v0;
    float o1 = BL0 * w4 + BL2 * w3 + BL4 * w2 + BL6 * w1
             + BH0 * v4 + BH2 * v3 + BH4 * v2 + BH6 * v1;
    float o2 = BL1 * w4 + BL3 * w3 + BL5 * w2 + BL7 * w1
             + BH1 * v4 + BH3 * v3 + BH5 * v2 + BH7 * v1;
    float o3 = BL0 * w5 + BL2 * w4 + BL4 * w3 + BL6 * w2
             + BH0 * v5 + BH2 * v4 + BH4 * v3 + BH6 * v2;
    // Group B: outputs j = 8t+4 .. 8t+7 (window w2..w7 / v2..v7)
    float o4 = BL1 * w5 + BL3 * w4 + BL5 * w3 + BL7 * w2
             + BH1 * v5 + BH3 * v4 + BH5 * v3 + BH7 * v2;
    float o5 = BL0 * w6 + BL2 * w5 + BL4 * w4 + BL6 * w3
             + BH0 * v6 + BH2 * v5 + BH4 * v4 + BH6 * v3;
    float o6 = BL1 * w6 + BL3 * w5 + BL5 * w4 + BL7 * w3
             + BH1 * v6 + BH3 * v5 + BH5 * v4 + BH7 * v3;
    float o7 = BL0 * w7 + BL2 * w6 + BL4 * w5 + BL6 * w4
             + BH0 * v7 + BH2 * v6 + BH4 * v5 + BH6 * v4;

    vfloat4* outv = (vfloat4*)(out + (size_t)row * LOUT + 8 * (size_t)t);
    vfloat4 pa = {o0, o1, o2, o3};
    vfloat4 pb = {o4, o5, o6, o7};
    __builtin_nontemporal_store(pa, outv + 0);
    __builtin_nontemporal_store(pb, outv + 1);
}

extern "C" void kernel_launch(void* const* d_in, const int* in_sizes, int n_in,
                              void* d_out, int out_size, void* d_ws, size_t ws_size,
                              hipStream_t stream)
{
    const float* L = (const float*)d_in[0];
    const float* H = (const float*)d_in[1];
    float* out = (float*)d_out;

    const int total_threads = NROWS * TPER;           // 524,288
    const int blocks = total_threads / 256;           // 2048
    idwt_db4_kernel<<<blocks, 256, 0, stream>>>(L, H, out);
}